// Round 1
// baseline (30.903 us; speedup 1.0000x reference)
//
#include <hip/hip_runtime.h>
#include <math.h>

#define A_HEADS 8
#define KK 3
#define BB 32
#define HH 160
#define WW 160
#define NW 72            // A*K*K output channels of the conv
#define WELEMS (NW * 9)  // 648 weight floats

__global__ __launch_bounds__(256) void vi_kernel(
    const float* __restrict__ values,
    const float* __restrict__ rewards,
    const float* __restrict__ weight,
    float* __restrict__ out)
{
    __shared__ float wsh[WELEMS];

    int tid = threadIdx.y * blockDim.x + threadIdx.x;
    for (int i = tid; i < WELEMS; i += 256) {
        wsh[i] = weight[i];
    }
    __syncthreads();

    int w  = blockIdx.x * blockDim.x + threadIdx.x;   // 0..159 (grid.x=5, bdim.x=32)
    int hb = blockIdx.y * blockDim.y + threadIdx.y;   // global row in [0, B*H)
    int h  = hb % HH;
    int b  = hb / HH;

    const float* vbase = values  + b * (HH * WW);
    const float* rbase = rewards + b * (HH * WW);

    // Build 3x3 zero-padded patch of rv = values + rewards around (h, w).
    float patch[9];
    #pragma unroll
    for (int di = 0; di < 3; ++di) {
        int hh = h + di - 1;
        bool hok = (hh >= 0) && (hh < HH);
        #pragma unroll
        for (int dj = 0; dj < 3; ++dj) {
            int ww = w + dj - 1;
            bool ok = hok && (ww >= 0) && (ww < WW);
            float val = 0.0f;
            if (ok) {
                int off = hh * WW + ww;
                val = vbase[off] + rbase[off];
            }
            patch[di * 3 + dj] = val;
        }
    }

    float best = -INFINITY;
    #pragma unroll
    for (int a = 0; a < A_HEADS; ++a) {
        float logits[9];
        float mx = -INFINITY;
        #pragma unroll
        for (int i = 0; i < 9; ++i) {
            const float* wp = &wsh[(a * 9 + i) * 9];
            float s = 0.0f;
            #pragma unroll
            for (int j = 0; j < 9; ++j) {
                s = fmaf(patch[j], wp[j], s);
            }
            logits[i] = s;
            mx = fmaxf(mx, s);
        }
        float den = 0.0f;
        float num = 0.0f;
        #pragma unroll
        for (int i = 0; i < 9; ++i) {
            float e = __expf(logits[i] - mx);
            den += e;
            num = fmaf(patch[i], e, num);
        }
        best = fmaxf(best, num / den);
    }

    out[hb * WW + w] = best;
}

extern "C" void kernel_launch(void* const* d_in, const int* in_sizes, int n_in,
                              void* d_out, int out_size, void* d_ws, size_t ws_size,
                              hipStream_t stream)
{
    const float* values  = (const float*)d_in[0];
    const float* rewards = (const float*)d_in[1];
    const float* weight  = (const float*)d_in[2];
    float* out = (float*)d_out;

    dim3 block(32, 8);
    dim3 grid(WW / 32, (BB * HH) / 8);   // (5, 640)
    vi_kernel<<<grid, block, 0, stream>>>(values, rewards, weight, out);
}